// Round 1
// baseline (19694.037 us; speedup 1.0000x reference)
//
#include <hip/hip_runtime.h>
#include <cmath>

constexpr int H = 256;
constexpr int SLEN = 50;
constexpr int ROWF = SLEN * H;   // 12800 floats per sequence
// per-decoding sizes
constexpr long SCORES_PER_D = 3200L * 50 * 50;   // 8,000,000
constexpr long OUT_PER_D    = SCORES_PER_D + 3200L * 50;  // 8,160,000

__device__ __forceinline__ float sigf(float x) { return 1.0f / (1.0f + expf(-x)); }

// ---------------- weight prep: combined/reordered B matrices ----------------
// Bg[m][col] (512x1024): col = 4*k + g  <->  original gate row g*256+k of [W_ih | W_hh]
// bias[col] = b_ih + b_hh ; B1[h][k] = W1[k][h] ; B2[m][k] = W2[k][m]
__global__ __launch_bounds__(256) void prep_kernel(
    const float* __restrict__ W_ih, const float* __restrict__ W_hh,
    const float* __restrict__ b_ih, const float* __restrict__ b_hh,
    const float* __restrict__ W1, const float* __restrict__ W2,
    float* __restrict__ Bg, float* __restrict__ bias,
    float* __restrict__ B1, float* __restrict__ B2)
{
  int idx = blockIdx.x * 256 + threadIdx.x;
  if (idx < 524288) {
    int m = idx >> 10, col = idx & 1023;
    int k = col >> 2, g = col & 3;
    int ro = g * 256 + k;
    Bg[idx] = (m < 256) ? W_ih[ro * 256 + m] : W_hh[ro * 256 + (m - 256)];
  } else if (idx < 525312) {
    int col = idx - 524288;
    int k = col >> 2, g = col & 3;
    bias[col] = b_ih[g * 256 + k] + b_hh[g * 256 + k];
  } else if (idx < 590848) {
    int j = idx - 525312;
    int m = j >> 8, k = j & 255;
    B1[j] = W1[k * 256 + m];
  } else if (idx < 656384) {
    int j = idx - 590848;
    int m = j >> 8, k = j & 255;
    B2[j] = W2[k * 256 + m];
  }
}

// ---------------- init: h0 = sum_s enc[n,s,:], x0 = 0 ----------------
__global__ __launch_bounds__(256) void init_state(
    const float* __restrict__ e0, const float* __restrict__ e1, const float* __restrict__ e2,
    float* __restrict__ XA, float* __restrict__ cst)
{
  int n = blockIdx.x;
  int d = (n >= 6400) ? 2 : (n >= 3200) ? 1 : 0;
  int nl = n - d * 3200;
  const float* ep = (d == 0 ? e0 : d == 1 ? e1 : e2) + (size_t)nl * ROWF;
  int k = threadIdx.x;
  float s = 0.f;
  for (int t = 0; t < SLEN; ++t) s += ep[t * H + k];
  XA[(size_t)n * 512 + k] = 0.f;
  XA[(size_t)n * 512 + 256 + k] = s;
  cst[(size_t)n * 256 + k] = s;
}

// ---------------- tiled fp32 GEMM: C[M,N] = A[M,K] * B[K,N] ----------------
// BM=64, BN=128, BK=32, 256 threads; thread = (tr=tid>>5)[8 rows] x (tc=tid&31)[4 cols]
// EPI==0: store C.  EPI==1: fused LSTM pointwise (cols are i,f,g,o quads per hidden unit).
template <int EPI>
__global__ __launch_bounds__(256) void gemm_k(
    const float* __restrict__ A, int lda,
    const float* __restrict__ B, int ldb,
    float* __restrict__ C, int ldc,
    const float* __restrict__ bias,
    float* __restrict__ cst, float* __restrict__ hout,
    int K)
{
  __shared__ float As[64][32];
  __shared__ float Bs[32][128];
  const int tid = threadIdx.x;
  const int tr = tid >> 5, tc = tid & 31;
  const size_t row0 = (size_t)blockIdx.x * 64;
  const int col0 = blockIdx.y * 128;
  float4 acc[8];
#pragma unroll
  for (int i = 0; i < 8; ++i) acc[i] = make_float4(0.f, 0.f, 0.f, 0.f);

  for (int k0 = 0; k0 < K; k0 += 32) {
#pragma unroll
    for (int i = 0; i < 8; ++i) {
      int idx = tid + i * 256;
      As[idx >> 5][idx & 31] = A[(row0 + (idx >> 5)) * (size_t)lda + k0 + (idx & 31)];
    }
#pragma unroll
    for (int i = 0; i < 16; ++i) {
      int idx = tid + i * 256;
      Bs[idx >> 7][idx & 127] = B[(size_t)(k0 + (idx >> 7)) * ldb + col0 + (idx & 127)];
    }
    __syncthreads();
#pragma unroll
    for (int kk = 0; kk < 32; ++kk) {
      const float4 bv = *(const float4*)&Bs[kk][tc * 4];
#pragma unroll
      for (int i = 0; i < 8; ++i) {
        float a = As[tr * 8 + i][kk];
        acc[i].x = fmaf(a, bv.x, acc[i].x);
        acc[i].y = fmaf(a, bv.y, acc[i].y);
        acc[i].z = fmaf(a, bv.z, acc[i].z);
        acc[i].w = fmaf(a, bv.w, acc[i].w);
      }
    }
    __syncthreads();
  }

  if (EPI == 0) {
#pragma unroll
    for (int i = 0; i < 8; ++i) {
      size_t n = row0 + tr * 8 + i;
      *(float4*)&C[n * (size_t)ldc + col0 + tc * 4] = acc[i];
    }
  } else {
    const int ku = (col0 >> 2) + tc;              // hidden unit index
    const float4 bb = *(const float4*)&bias[col0 + tc * 4];
#pragma unroll
    for (int i = 0; i < 8; ++i) {
      size_t n = row0 + tr * 8 + i;
      float ig = sigf(acc[i].x + bb.x);
      float fg = sigf(acc[i].y + bb.y);
      float gg = tanhf(acc[i].z + bb.z);
      float og = sigf(acc[i].w + bb.w);
      float cold = cst[n * 256 + ku];
      float cn = fg * cold + ig * gg;
      cst[n * 256 + ku] = cn;
      hout[n * 512 + ku] = og * tanhf(cn);        // hout pre-offset: X_next + 256
    }
  }
}

// ---------------- attention + softmax + argmax + x gather ----------------
__global__ __launch_bounds__(256) void attn_step(
    const float* __restrict__ enct, const float* __restrict__ dec,
    const float* __restrict__ vtp,
    const float* __restrict__ e0, const float* __restrict__ e1, const float* __restrict__ e2,
    float* __restrict__ Xnext, float* __restrict__ out, int t)
{
  int n = blockIdx.x;
  int d = (n >= 6400) ? 2 : (n >= 3200) ? 1 : 0;
  int nl = n - d * 3200;
  const float* encp = (d == 0 ? e0 : d == 1 ? e1 : e2) + (size_t)nl * ROWF;
  const float* ep = enct + (size_t)n * ROWF;
  const float* dp = dec + (size_t)n * 256;
  const int tid = threadIdx.x;
  const int wave = tid >> 6, lane = tid & 63;

  float df[4], vf[4];
#pragma unroll
  for (int j = 0; j < 4; ++j) { df[j] = dp[lane + 64 * j]; vf[j] = vtp[lane + 64 * j]; }

  __shared__ float u[64];
  __shared__ int sidx;

  for (int s = wave; s < SLEN; s += 4) {
    const float* row = ep + s * 256;
    float p = 0.f;
#pragma unroll
    for (int j = 0; j < 4; ++j) p = fmaf(vf[j], tanhf(row[lane + 64 * j] + df[j]), p);
#pragma unroll
    for (int off = 32; off >= 1; off >>= 1) p += __shfl_xor(p, off);
    if (lane == 0) u[s] = p;
  }
  __syncthreads();

  if (tid < 64) {
    float v = (lane < SLEN) ? u[lane] : -INFINITY;
    float m = v;
#pragma unroll
    for (int off = 32; off >= 1; off >>= 1) m = fmaxf(m, __shfl_xor(m, off));
    float e = (lane < SLEN) ? expf(v - m) : 0.f;
    float ssum = e;
#pragma unroll
    for (int off = 32; off >= 1; off >>= 1) ssum += __shfl_xor(ssum, off);
    float sc = e / ssum;
    size_t ob = (size_t)d * OUT_PER_D;
    if (lane < SLEN) out[ob + (size_t)nl * 2500 + (size_t)t * 50 + lane] = sc;
    float scv = (lane < SLEN) ? sc : -INFINITY;
    float mx = scv;
#pragma unroll
    for (int off = 32; off >= 1; off >>= 1) mx = fmaxf(mx, __shfl_xor(mx, off));
    unsigned long long bal = __ballot(lane < SLEN && scv == mx);
    int am = __ffsll(bal) - 1;   // first occurrence of max, like jnp.argmax
    if (lane == 0) {
      sidx = am;
      out[ob + SCORES_PER_D + (size_t)nl * 50 + t] = (float)am;
    }
  }
  __syncthreads();

  int idx = sidx;
  Xnext[(size_t)n * 512 + tid] = encp[(size_t)idx * 256 + tid];
}

// ---------------- driver ----------------
extern "C" void kernel_launch(void* const* d_in, const int* in_sizes, int n_in,
                              void* d_out, int out_size, void* d_ws, size_t ws_size,
                              hipStream_t stream) {
  const float* home = (const float*)d_in[0];
  const float* vis  = (const float*)d_in[1];
  const float* team = (const float*)d_in[2];
  const float* W_ih = (const float*)d_in[3];
  const float* W_hh = (const float*)d_in[4];
  const float* b_ih = (const float*)d_in[5];
  const float* b_hh = (const float*)d_in[6];
  const float* W1   = (const float*)d_in[7];
  const float* W2   = (const float*)d_in[8];
  const float* vtp  = (const float*)d_in[9];
  float* out = (float*)d_out;

  float* ws = (float*)d_ws;
  float* Bg   = ws;                    // 512*1024           = 524288
  float* bias = Bg + 524288;           // 1024
  float* B1   = bias + 1024;           // 256*256            = 65536
  float* B2   = B1 + 65536;            // 65536
  float* XA   = B2 + 65536;            // 9600*512           = 4915200
  float* XB   = XA + 4915200;          // 4915200
  float* cst  = XB + 4915200;          // 9600*256           = 2457600
  float* dec  = cst + 2457600;         // 2457600
  float* enct = dec + 2457600;         // 9600*50*256        = 122880000

  prep_kernel<<<2564, 256, 0, stream>>>(W_ih, W_hh, b_ih, b_hh, W1, W2, Bg, bias, B1, B2);
  init_state<<<9600, 256, 0, stream>>>(home, vis, team, XA, cst);

  // enc_t = enc @ W1^T  (per decoding: M=160000, K=256, N=256)
  const float* encs[3] = {home, vis, team};
  for (int d = 0; d < 3; ++d) {
    gemm_k<0><<<dim3(2500, 2), 256, 0, stream>>>(
        encs[d], 256, B1, 256, enct + (size_t)d * 40960000, 256,
        nullptr, nullptr, nullptr, 256);
  }

  for (int t = 0; t < SLEN; ++t) {
    float* Xc = (t & 1) ? XB : XA;
    float* Xn = (t & 1) ? XA : XB;
    // gates = [x|h] @ Bg + bias ; fused LSTM -> writes c, h(into Xn cols 256:511)
    gemm_k<1><<<dim3(150, 8), 256, 0, stream>>>(
        Xc, 512, Bg, 1024, nullptr, 0, bias, cst, Xn + 256, 512);
    // dec = h_new @ W2^T
    gemm_k<0><<<dim3(150, 2), 256, 0, stream>>>(
        Xn + 256, 512, B2, 256, dec, 256, nullptr, nullptr, nullptr, 256);
    // attention + softmax + argmax + gather x_next (into Xn cols 0:255)
    attn_step<<<9600, 256, 0, stream>>>(
        enct, dec, vtp, home, vis, team, Xn, out, t);
  }
}